// Round 24
// baseline (30.844 us; speedup 1.0000x reference)
//
#include <hip/hip_runtime.h>

// Maj3: out[b,o,h,w] = sum_{kh,c} sign( sum_{kw} x[b,c,h+kh-1,w+kw-1] * W[o,kw,kh,c] )
// x: (4,64,56,56) f32; W: (64,3,3,64) f32; out: (4,64,56,56) f32.
// Bit-exactness vs numpy required (threshold 1.36, integer output): contract(off),
// reference mul/add order per sign. Padded rows staged as 0.0 -> sums are +-0;
// the (s < 0) predicate counts neither, and base=nvalid*64 excludes them.
//
// R24: occupancy line closed (R22 spill @cap64; R23 8-wave OG=2 = 29.9 > R21
// 27.9 — not occupancy-limited). The proven lever is fixed-cost amortization
// (R21 h-pair: -2.6us). Push it: FOUR h-rows per block. Slab [6][64][17]
// (25.5KB) serves h0..h0+3: staging per output halves again, ds_reads per
// output-pair 2.0 -> 1.5, sign arithmetic per output unchanged. Working set
// ~90 VGPR -> cap-128 (256,4), the proven-clean regime. Grid (56,4,4)=896
// = 3.5 blk/CU (balance proven ~free: R15==R18); LDS allows 6 resident.

#define Cn 64
#define Hn 56
#define Wn 56
#define On 64
#define OG 4        // output channels per wave (proven spill-free budget)
#define NH 4        // fused h-rows per block
#define PIX 14      // pixels per wave (quarter row)
#define SLABW 16    // staged taps per row: w0-1 .. w0+14 (pow2)
#define SLABP 17    // padded stride (odd -> 2 lanes/bank = conflict-free)

// v_writelane_b32: write wave-uniform `val` into lane `LANE` of `dst`.
#define WRITELANE(dst, val, LANE)                                             \
    asm("v_writelane_b32 %0, %1, " #LANE                                      \
        : "+v"(dst) : "s"(val))

// One-instruction ballot: mask[lane] = (v < 0.0f). VOP3 v_cmp, SGPR-pair dest,
// inline-constant 0 src1. Non-volatile -> schedulable.
#define BALLOT_LT0(mask, v)                                                   \
    asm("v_cmp_lt_f32 %0, %1, 0" : "=s"(mask) : "v"(v))

__global__ __launch_bounds__(256, 4)
void maj3_kernel(const float* __restrict__ x,
                 const float* __restrict__ wt,
                 float* __restrict__ out)
{
#pragma clang fp contract(off)
    __shared__ float slab[NH + 2][Cn][SLABP];   // rows h0-1 .. h0+4

    const int lane  = threadIdx.x & 63;    // = channel c
    const int wave  = __builtin_amdgcn_readfirstlane((int)(threadIdx.x >> 6)); // 0..3
    const int b     = blockIdx.x / 14;     // 4 batches x 14 h-quads
    const int hq    = blockIdx.x - b * 14;
    const int h0    = hq * NH;             // rows h0 .. h0+3
    const int w0    = blockIdx.y * PIX;    // 0,14,28,42
    const int obase = blockIdx.z * 16 + wave * OG;   // this wave's o range

    // Stage x[b, :, h0-1..h0+4, w0-1..w0+14] into slab; pads staged as 0.0f.
    // 6144 elements over 256 threads = 24 iterations, pow-2 index math.
    const float* xb = x + b * (Cn * Hn * Wn);
    for (int i = threadIdx.x; i < (NH + 2) * Cn * SLABW; i += 256) {
        const int ws  = i & (SLABW - 1);
        const int t   = i >> 4;
        const int c   = t & (Cn - 1);
        const int r   = t >> 6;            // 0..5
        const int row = h0 + r - 1;
        const int w   = w0 - 1 + ws;
        float v = 0.0f;
        if (row >= 0 && row < Hn && (unsigned)w < (unsigned)Wn)
            v = xb[(c * Hn + row) * Wn + w];
        slab[r][c][ws] = v;
    }

    // This wave's weights, lane = c: W[o,kw,kh,c] = wt[((o*3+kw)*3+kh)*64+c].
    // 36 coalesced 256B loads, once; lives in 36 VGPRs for the whole kernel.
    float wreg[OG][3][3];
    #pragma unroll
    for (int oo = 0; oo < OG; ++oo)
        #pragma unroll
        for (int kw = 0; kw < 3; ++kw)
            #pragma unroll
            for (int kh = 0; kh < 3; ++kh)
                wreg[oo][kh][kw] = wt[(((obase + oo) * 3 + kw) * 3 + kh) * Cn + lane];

    __syncthreads();

    int vcnt[NH][OG];                      // lane p: neg-count, rows h0..h0+3
    #pragma unroll
    for (int ho = 0; ho < NH; ++ho)
        #pragma unroll
        for (int oo = 0; oo < OG; ++oo) vcnt[ho][oo] = 0;

    // Sliding 3-tap windows across 6 slab rows (SSA renames under unroll).
    float xl[NH + 2], xm[NH + 2];
    #pragma unroll
    for (int r = 0; r < NH + 2; ++r) {
        xl[r] = slab[r][lane][0];
        xm[r] = slab[r][lane][1];
    }

#define PBODY(P)                                                              \
    do {                                                                      \
        float xc[NH + 2];                                                     \
        _Pragma("unroll")                                                     \
        for (int r = 0; r < NH + 2; ++r) xc[r] = slab[r][lane][(P) + 2];      \
        _Pragma("unroll")                                                     \
        for (int ho = 0; ho < NH; ++ho) {                                     \
            _Pragma("unroll")                                                 \
            for (int oo = 0; oo < OG; ++oo) {                                 \
                int cnt = 0;                                                  \
                _Pragma("unroll")                                             \
                for (int kh = 0; kh < 3; ++kh) {                              \
                    const float s = (xl[ho + kh] * wreg[oo][kh][0] +          \
                                     xm[ho + kh] * wreg[oo][kh][1])           \
                                  + xc[ho + kh] * wreg[oo][kh][2];            \
                    unsigned long long m;                                     \
                    BALLOT_LT0(m, s);                                         \
                    cnt += (int)__builtin_popcountll(m);                      \
                }                                                             \
                const int cs = __builtin_amdgcn_readfirstlane(cnt);          \
                WRITELANE(vcnt[ho][oo], cs, P);                               \
            }                                                                 \
        }                                                                     \
        _Pragma("unroll")                                                     \
        for (int r = 0; r < NH + 2; ++r) { xl[r] = xm[r]; xm[r] = xc[r]; }    \
    } while (0)

    PBODY(0);  PBODY(1);  PBODY(2);  PBODY(3);  PBODY(4);  PBODY(5);
    PBODY(6);  PBODY(7);  PBODY(8);  PBODY(9);  PBODY(10); PBODY(11);
    PBODY(12); PBODY(13);

    // out = nvalid*64 - 2*negcount. Padded slab rows are zero -> sums +-0 ->
    // (s<0) never counts them; base excludes them.
    if (lane < PIX) {
        #pragma unroll
        for (int ho = 0; ho < NH; ++ho) {
            const int h = h0 + ho;
            const int nvalid = 3 - (h == 0) - (h == Hn - 1);
            const float base = (float)(nvalid * Cn);
            float* ob = out + ((b * On + obase) * Hn + h) * Wn + w0 + lane;
            #pragma unroll
            for (int oo = 0; oo < OG; ++oo)
                ob[oo * Hn * Wn] = base - 2.0f * (float)vcnt[ho][oo];
        }
    }
}

extern "C" void kernel_launch(void* const* d_in, const int* in_sizes, int n_in,
                              void* d_out, int out_size, void* d_ws, size_t ws_size,
                              hipStream_t stream) {
    const float* x  = (const float*)d_in[0];
    const float* wt = (const float*)d_in[1];
    float* o        = (float*)d_out;
    dim3 grid(56, 4, 4);   // (b,h-quad) x w-quarter x o-quarter
    maj3_kernel<<<grid, dim3(256), 0, stream>>>(x, wt, o);
}

// Round 25
// 27.942 us; speedup vs baseline: 1.1038x; 1.1038x over previous
//
#include <hip/hip_runtime.h>

// Maj3: out[b,o,h,w] = sum_{kh,c} sign( sum_{kw} x[b,c,h+kh-1,w+kw-1] * W[o,kw,kh,c] )
// x: (4,64,56,56) f32; W: (64,3,3,64) f32; out: (4,64,56,56) f32.
// Bit-exactness vs numpy required (threshold 1.36, integer output): contract(off),
// reference mul/add order per sign. Padded rows staged as 0.0 -> sums are +-0;
// the (s < 0) predicate counts neither, and base=nvalid*64 excludes them.
//
// R25 = R21 (the measured optimum, 27.9us), reverting R24's NH=4 (30.8us —
// amortization knee passed: NH=1:30.5, NH=2:27.9, NH=4:30.8).
// Final design: lane = channel c (sign-count axis). Weights per-lane in 36
// VGPRs, loaded once (zero main-loop weight traffic). Signs counted 64/instr
// via inline-asm v_cmp ballot + s_bcnt1 + writelane. Two h-rows fused per
// block: slab [4][64][17] (17.4KB), shared-row column reads CSE'd, staging
// -29%/output. Grid (112,4,4)=1792=7 blocks/CU, cap-128 via (256,4) — the
// proven spill-free regime (64-cap spills: R22; (256,6) 85-cap spills: R17).

#define Cn 64
#define Hn 56
#define Wn 56
#define On 64
#define OG 4        // output channels per wave (proven spill-free budget)
#define PIX 14      // pixels per wave (quarter row)
#define SLABW 16    // staged taps per row: w0-1 .. w0+14 (pow2)
#define SLABP 17    // padded stride (odd -> 2 lanes/bank = conflict-free)

// v_writelane_b32: write wave-uniform `val` into lane `LANE` of `dst`.
#define WRITELANE(dst, val, LANE)                                             \
    asm("v_writelane_b32 %0, %1, " #LANE                                      \
        : "+v"(dst) : "s"(val))

// One-instruction ballot: mask[lane] = (v < 0.0f). VOP3 v_cmp, SGPR-pair dest,
// inline-constant 0 src1. Non-volatile -> schedulable.
#define BALLOT_LT0(mask, v)                                                   \
    asm("v_cmp_lt_f32 %0, %1, 0" : "=s"(mask) : "v"(v))

__global__ __launch_bounds__(256, 4)
void maj3_kernel(const float* __restrict__ x,
                 const float* __restrict__ wt,
                 float* __restrict__ out)
{
#pragma clang fp contract(off)
    __shared__ float slab[4][Cn][SLABP];   // rows h0-1 .. h0+2

    const int lane  = threadIdx.x & 63;    // = channel c
    const int wave  = __builtin_amdgcn_readfirstlane((int)(threadIdx.x >> 6)); // 0..3
    const int b     = blockIdx.x / 28;     // 4 batches x 28 h-pairs
    const int hp    = blockIdx.x - b * 28;
    const int h0    = hp * 2;              // even row; h1 = h0+1 (odd, <=55)
    const int w0    = blockIdx.y * PIX;    // 0,14,28,42
    const int obase = blockIdx.z * 16 + wave * OG;   // this wave's o range

    // Stage x[b, :, h0-1..h0+2, w0-1..w0+14] into slab; pads staged as 0.0f.
    // 4096 elements over 256 threads = 16 iterations, pow-2 index math.
    const float* xb = x + b * (Cn * Hn * Wn);
    for (int i = threadIdx.x; i < 4 * Cn * SLABW; i += 256) {
        const int ws  = i & (SLABW - 1);
        const int t   = i >> 4;
        const int c   = t & (Cn - 1);
        const int r   = t >> 6;            // 0..3
        const int row = h0 + r - 1;
        const int w   = w0 - 1 + ws;
        float v = 0.0f;
        if (row >= 0 && row < Hn && (unsigned)w < (unsigned)Wn)
            v = xb[(c * Hn + row) * Wn + w];
        slab[r][c][ws] = v;
    }

    // This wave's weights, lane = c: W[o,kw,kh,c] = wt[((o*3+kw)*3+kh)*64+c].
    // 36 coalesced 256B loads, once; lives in 36 VGPRs for the whole kernel.
    float wreg[OG][3][3];
    #pragma unroll
    for (int oo = 0; oo < OG; ++oo)
        #pragma unroll
        for (int kw = 0; kw < 3; ++kw)
            #pragma unroll
            for (int kh = 0; kh < 3; ++kh)
                wreg[oo][kh][kw] = wt[(((obase + oo) * 3 + kw) * 3 + kh) * Cn + lane];

    __syncthreads();

    int vcnt[2][OG];                       // lane p: neg-count, rows h0/h1
    #pragma unroll
    for (int ho = 0; ho < 2; ++ho)
        #pragma unroll
        for (int oo = 0; oo < OG; ++oo) vcnt[ho][oo] = 0;

    // Sliding 3-tap windows across 4 slab rows (SSA renames under unroll).
    float xl[4], xm[4];
    #pragma unroll
    for (int r = 0; r < 4; ++r) {
        xl[r] = slab[r][lane][0];
        xm[r] = slab[r][lane][1];
    }

#define PBODY(P)                                                              \
    do {                                                                      \
        float xc[4];                                                          \
        _Pragma("unroll")                                                     \
        for (int r = 0; r < 4; ++r) xc[r] = slab[r][lane][(P) + 2];           \
        _Pragma("unroll")                                                     \
        for (int ho = 0; ho < 2; ++ho) {                                      \
            _Pragma("unroll")                                                 \
            for (int oo = 0; oo < OG; ++oo) {                                 \
                int cnt = 0;                                                  \
                _Pragma("unroll")                                             \
                for (int kh = 0; kh < 3; ++kh) {                              \
                    const float s = (xl[ho + kh] * wreg[oo][kh][0] +          \
                                     xm[ho + kh] * wreg[oo][kh][1])           \
                                  + xc[ho + kh] * wreg[oo][kh][2];            \
                    unsigned long long m;                                     \
                    BALLOT_LT0(m, s);                                         \
                    cnt += (int)__builtin_popcountll(m);                      \
                }                                                             \
                const int cs = __builtin_amdgcn_readfirstlane(cnt);          \
                WRITELANE(vcnt[ho][oo], cs, P);                               \
            }                                                                 \
        }                                                                     \
        _Pragma("unroll")                                                     \
        for (int r = 0; r < 4; ++r) { xl[r] = xm[r]; xm[r] = xc[r]; }         \
    } while (0)

    PBODY(0);  PBODY(1);  PBODY(2);  PBODY(3);  PBODY(4);  PBODY(5);
    PBODY(6);  PBODY(7);  PBODY(8);  PBODY(9);  PBODY(10); PBODY(11);
    PBODY(12); PBODY(13);

    // out = nvalid*64 - 2*negcount. h0 even in [0,54]: pad only when h0==0;
    // h1 odd in [1,55]: pad only when h1==55. Padded slab rows are zero ->
    // their sums are +-0 -> (s<0) never counts them.
    if (lane < PIX) {
        #pragma unroll
        for (int ho = 0; ho < 2; ++ho) {
            const int h = h0 + ho;
            const int nvalid = 3 - (h == 0) - (h == Hn - 1);
            const float base = (float)(nvalid * Cn);
            float* ob = out + ((b * On + obase) * Hn + h) * Wn + w0 + lane;
            #pragma unroll
            for (int oo = 0; oo < OG; ++oo)
                ob[oo * Hn * Wn] = base - 2.0f * (float)vcnt[ho][oo];
        }
    }
}

extern "C" void kernel_launch(void* const* d_in, const int* in_sizes, int n_in,
                              void* d_out, int out_size, void* d_ws, size_t ws_size,
                              hipStream_t stream) {
    const float* x  = (const float*)d_in[0];
    const float* wt = (const float*)d_in[1];
    float* o        = (float*)d_out;
    dim3 grid(112, 4, 4);   // (b,h-pair) x w-quarter x o-quarter
    maj3_kernel<<<grid, dim3(256), 0, stream>>>(x, wt, o);
}